// Round 1
// baseline (1529.856 us; speedup 1.0000x reference)
//
#include <hip/hip_runtime.h>

#define B_ 32
#define D_ 128
#define LC 2048
#define LQ 512

#define NEGINF (-3.0e38f)

// ---------- K0: outv[b,x] = sum_d X[b,d,x] * w[d]  (X layout [B][D][L]) ----------
__global__ void k_dotw(const float* __restrict__ X, const float* __restrict__ w,
                       float* __restrict__ outv, int L) {
    int idx = blockIdx.x * 256 + threadIdx.x;   // b*L + x
    int b = idx / L, x = idx - b * L;
    const float* Xp = X + (size_t)b * D_ * L + x;
    float acc = 0.f;
#pragma unroll 8
    for (int dd = 0; dd < D_; ++dd) acc += Xp[(size_t)dd * L] * w[dd];
    outv[idx] = acc;
}

// ---------- K1: S[b,c,q] = s0[b,c] + s1[b,q] + bias + sum_d C[b,d,c]*wmul[d]*Q[b,d,q]
// tile: 32 c x 64 q, block 256, each thread 8 q-outputs
__global__ void k_S(const float* __restrict__ C, const float* __restrict__ Q,
                    const float* __restrict__ wmul, const float* __restrict__ bias,
                    const float* __restrict__ s0, const float* __restrict__ s1,
                    float* __restrict__ S) {
    int b = blockIdx.y;
    int qTile = blockIdx.x & 7;       // LQ/64 = 8
    int cTile = blockIdx.x >> 3;      // LC/32 = 64
    int c0 = cTile * 32, q0 = qTile * 64;
    int tid = threadIdx.x;

    __shared__ float Cs[16][32];
    __shared__ float Qs[16][64];

    const float* Cb = C + (size_t)b * D_ * LC;
    const float* Qb = Q + (size_t)b * D_ * LQ;

    int c_l = tid >> 3;               // 0..31
    int q_l0 = (tid & 7) * 8;         // 0..56

    float acc[8];
#pragma unroll
    for (int k = 0; k < 8; ++k) acc[k] = 0.f;

    for (int d0 = 0; d0 < D_; d0 += 16) {
        __syncthreads();
        {   // Cs: 16x32, pre-scaled by w_mul
            int i = tid >> 5, j = tid & 31;
            Cs[i][j]     = Cb[(size_t)(d0 + i) * LC + c0 + j] * wmul[d0 + i];
            Cs[i + 8][j] = Cb[(size_t)(d0 + i + 8) * LC + c0 + j] * wmul[d0 + i + 8];
        }
        {   // Qs: 16x64
            int i = tid >> 6, j = tid & 63;
#pragma unroll
            for (int r = 0; r < 4; ++r)
                Qs[i + r * 4][j] = Qb[(size_t)(d0 + i + r * 4) * LQ + q0 + j];
        }
        __syncthreads();
#pragma unroll
        for (int i = 0; i < 16; ++i) {
            float a = Cs[i][c_l];
#pragma unroll
            for (int k = 0; k < 8; ++k) acc[k] += a * Qs[i][q_l0 + k];
        }
    }
    float base = s0[b * LC + c0 + c_l] + bias[0];
    float* Sp = S + (size_t)b * LC * LQ + (size_t)(c0 + c_l) * LQ + q0 + q_l0;
    const float* s1p = s1 + b * LQ + q0 + q_l0;
#pragma unroll
    for (int k = 0; k < 8; ++k) Sp[k] = base + s1p[k] + acc[k];
}

// ---------- K2: per-row (over q) masked max & sum(exp). one wave per row ----------
__global__ void k_rowstats(const float* __restrict__ S, const int* __restrict__ Qmask,
                           float* __restrict__ rowmax, float* __restrict__ rowsum) {
    int row = blockIdx.x * 4 + (threadIdx.x >> 6);   // b*LC + c
    int lane = threadIdx.x & 63;
    int b = row / LC;
    const float* Sp = S + (size_t)row * LQ;
    const int* qm = Qmask + b * LQ;
    float v[8]; int m[8];
#pragma unroll
    for (int k = 0; k < 8; ++k) {
        int q = lane + 64 * k;
        v[k] = Sp[q]; m[k] = qm[q];
    }
    float mx = NEGINF;
#pragma unroll
    for (int k = 0; k < 8; ++k) if (m[k]) mx = fmaxf(mx, v[k]);
#pragma unroll
    for (int off = 32; off > 0; off >>= 1) mx = fmaxf(mx, __shfl_xor(mx, off, 64));
    float s = 0.f;
#pragma unroll
    for (int k = 0; k < 8; ++k) if (m[k]) s += __expf(v[k] - mx);
#pragma unroll
    for (int off = 32; off > 0; off >>= 1) s += __shfl_xor(s, off, 64);
    if (lane == 0) { rowmax[row] = mx; rowsum[row] = s; }
}

// ---------- K3: per-column (over c) masked online max/sum ----------
__global__ void k_colstats(const float* __restrict__ S, const int* __restrict__ Cmask,
                           float* __restrict__ colmax, float* __restrict__ colsum) {
    int b = blockIdx.y;
    int q0 = blockIdx.x * 64;
    int tid = threadIdx.x;
    int ql = tid & 63, cg = tid >> 6;   // cg 0..3
    const float* Sb = S + (size_t)b * LC * LQ + q0 + ql;
    const int* cm = Cmask + b * LC;
    float m = NEGINF, l = 0.f;
    for (int c = cg; c < LC; c += 4) {
        if (cm[c]) {                      // wave-uniform branch
            float v = Sb[(size_t)c * LQ];
            float mn = fmaxf(m, v);
            l = l * __expf(m - mn) + __expf(v - mn);
            m = mn;
        }
    }
    __shared__ float Ms[4][64], Ls[4][64];
    Ms[cg][ql] = m; Ls[cg][ql] = l;
    __syncthreads();
    if (tid < 64) {
        float mm = Ms[0][ql], ll = Ls[0][ql];
#pragma unroll
        for (int g = 1; g < 4; ++g) {
            float m2 = Ms[g][ql], l2 = Ls[g][ql];
            float mn = fmaxf(mm, m2);
            ll = ll * __expf(mm - mn) + l2 * __expf(m2 - mn);
            mm = mn;
        }
        colmax[b * LQ + q0 + ql] = mm;
        colsum[b * LQ + q0 + ql] = ll;
    }
}

// ---------- K4: V2t[b,dd,q] = (1/colsum) * sum_c cm[c]*exp(S[b,c,q]-colmax)*C[b,dd,c]
// block: 64 q x 64 dd tile; thread: 1 q x 16 dd
__global__ void k_V2(const float* __restrict__ S, const float* __restrict__ C,
                     const int* __restrict__ Cmask,
                     const float* __restrict__ colmax, const float* __restrict__ colsum,
                     float* __restrict__ V2t) {
    int b = blockIdx.y;
    int qTile = blockIdx.x >> 1;      // 0..7
    int ddTile = blockIdx.x & 1;      // 0..1
    int q0 = qTile * 64, dd0 = ddTile * 64;
    int tid = threadIdx.x;
    int ql = tid & 63, dg = (tid >> 6) * 16;

    __shared__ float Ss[32][64];
    __shared__ float Cs[64][32];
    __shared__ float cmask_s[32];

    const float* Sb = S + (size_t)b * LC * LQ;
    const float* Cb = C + (size_t)b * D_ * LC;
    float cmax = colmax[b * LQ + q0 + ql];

    float acc[16];
#pragma unroll
    for (int k = 0; k < 16; ++k) acc[k] = 0.f;

    for (int c0 = 0; c0 < LC; c0 += 32) {
        __syncthreads();
#pragma unroll
        for (int r = 0; r < 8; ++r) {
            int idx = tid + r * 256;
            int i = idx >> 6, j = idx & 63;
            Ss[i][j] = Sb[(size_t)(c0 + i) * LQ + q0 + j];
        }
#pragma unroll
        for (int r = 0; r < 8; ++r) {
            int idx = tid + r * 256;
            int jj = idx >> 5, ii = idx & 31;
            Cs[jj][ii] = Cb[(size_t)(dd0 + jj) * LC + c0 + ii];
        }
        if (tid < 32) cmask_s[tid] = (float)Cmask[b * LC + c0 + tid];
        __syncthreads();
        float e[32];
#pragma unroll
        for (int i = 0; i < 32; ++i)
            e[i] = cmask_s[i] * __expf(Ss[i][ql] - cmax);
#pragma unroll
        for (int k = 0; k < 16; ++k) {
            float a = 0.f;
#pragma unroll
            for (int i = 0; i < 32; ++i) a += e[i] * Cs[dg + k][i];  // b128-friendly
            acc[k] += a;
        }
    }
    float scale = 1.f / colsum[b * LQ + q0 + ql];
    float* Vp = V2t + (size_t)b * D_ * LQ + q0 + ql;
#pragma unroll
    for (int k = 0; k < 16; ++k) Vp[(size_t)(dd0 + dg + k) * LQ] = acc[k] * scale;
}

// ---------- K5: fused A/Bm GEMM + epilogue.
// W = [Qt | V2] as [n][Lq], n in [0,256). block: 64 c x 64 n; thread: 1 c x 16 n
__global__ void k_out(const float* __restrict__ S, const float* __restrict__ Q,
                      const float* __restrict__ V2t, const float* __restrict__ C,
                      const int* __restrict__ Qmask,
                      const float* __restrict__ rowmax, const float* __restrict__ rowsum,
                      float* __restrict__ out) {
    int b = blockIdx.y;
    int nTile = blockIdx.x & 3;       // 0..3
    int cTile = blockIdx.x >> 2;      // 0..31
    int c0 = cTile * 64, n0 = nTile * 64;
    int tid = threadIdx.x;
    int cl = tid & 63, ng = (tid >> 6) * 16;

    __shared__ float Ss[64][33];      // [c][q], +1 pad breaks write conflicts
    __shared__ float Wt[64][32];      // [n][q]
    __shared__ float qmask_s[32];

    const float* Sb = S + (size_t)b * LC * LQ;
    const float* Qb = Q + (size_t)b * D_ * LQ;
    const float* Vb = V2t + (size_t)b * D_ * LQ;
    float rmax = rowmax[b * LC + c0 + cl];

    float acc[16];
#pragma unroll
    for (int k = 0; k < 16; ++k) acc[k] = 0.f;

    for (int q0 = 0; q0 < LQ; q0 += 32) {
        __syncthreads();
#pragma unroll
        for (int r = 0; r < 8; ++r) {
            int idx = tid + r * 256;
            int j = idx >> 5, i = idx & 31;
            Ss[j][i] = Sb[(size_t)(c0 + j) * LQ + q0 + i];
        }
#pragma unroll
        for (int r = 0; r < 8; ++r) {
            int idx = tid + r * 256;
            int j = idx >> 5, i = idx & 31;
            int n = n0 + j;
            Wt[j][i] = (n < 128) ? Qb[(size_t)n * LQ + q0 + i]
                                 : Vb[(size_t)(n - 128) * LQ + q0 + i];
        }
        if (tid < 32) qmask_s[tid] = (float)Qmask[b * LQ + q0 + tid];
        __syncthreads();
        float e[32];
#pragma unroll
        for (int i = 0; i < 32; ++i)
            e[i] = qmask_s[i] * __expf(Ss[cl][i] - rmax);
#pragma unroll
        for (int k = 0; k < 16; ++k) {
            float a = 0.f;
#pragma unroll
            for (int i = 0; i < 32; ++i) a += e[i] * Wt[ng + k][i];
            acc[k] += a;
        }
    }
    float rscale = 1.f / rowsum[b * LC + c0 + cl];
    int c = c0 + cl;
    const float* Cb = C + (size_t)b * D_ * LC + c;
    float* outb = out + (size_t)b * 4 * D_ * LC + c;
#pragma unroll
    for (int k = 0; k < 16; ++k) {
        int n = n0 + ng + k;          // wave-uniform
        float a = acc[k] * rscale;
        if (n < 128) {                // A part
            float cv = Cb[(size_t)n * LC];
            outb[(size_t)(128 + n) * LC] = a;         // A
            outb[(size_t)(256 + n) * LC] = cv * a;    // Ct*A
        } else {                      // Bm part
            int ddn = n - 128;
            float cv = Cb[(size_t)ddn * LC];
            outb[(size_t)(384 + ddn) * LC] = cv * a;  // Ct*Bm
        }
    }
}

// ---------- K6: out[b, 0:128, c] = C[b, :, c] ----------
__global__ void k_copy(const float* __restrict__ C, float* __restrict__ out) {
    int idx = blockIdx.x * 256 + threadIdx.x;   // over B*D*LC/4 float4s
    const int perB = D_ * LC / 4;
    int b = idx / perB, r = idx - b * perB;
    const float4* src = (const float4*)(C + (size_t)b * D_ * LC);
    float4* dst = (float4*)(out + (size_t)b * 4 * D_ * LC);
    dst[r] = src[r];
}

extern "C" void kernel_launch(void* const* d_in, const int* in_sizes, int n_in,
                              void* d_out, int out_size, void* d_ws, size_t ws_size,
                              hipStream_t stream) {
    const float* C     = (const float*)d_in[0];
    const float* Q     = (const float*)d_in[1];
    const int*   Cmask = (const int*)d_in[2];
    const int*   Qmask = (const int*)d_in[3];
    const float* w_c   = (const float*)d_in[4];
    const float* w_q   = (const float*)d_in[5];
    const float* w_mul = (const float*)d_in[6];
    const float* bias  = (const float*)d_in[7];
    float* out = (float*)d_out;
    float* ws  = (float*)d_ws;

    // workspace layout (floats): total ~35.9M floats = 143.6 MB
    float* S      = ws;                          // B*LC*LQ = 33554432
    float* s0     = S + (size_t)B_ * LC * LQ;    // B*LC
    float* s1     = s0 + B_ * LC;                // B*LQ
    float* rowmax = s1 + B_ * LQ;                // B*LC
    float* rowsum = rowmax + B_ * LC;            // B*LC
    float* colmax = rowsum + B_ * LC;            // B*LQ
    float* colsum = colmax + B_ * LQ;            // B*LQ
    float* V2t    = colsum + B_ * LQ;            // B*D*LQ = 2097152

    hipLaunchKernelGGL(k_dotw, dim3(B_ * LC / 256), dim3(256), 0, stream, C, w_c, s0, LC);
    hipLaunchKernelGGL(k_dotw, dim3(B_ * LQ / 256), dim3(256), 0, stream, Q, w_q, s1, LQ);
    hipLaunchKernelGGL(k_S, dim3((LC / 32) * (LQ / 64), B_), dim3(256), 0, stream,
                       C, Q, w_mul, bias, s0, s1, S);
    hipLaunchKernelGGL(k_rowstats, dim3(B_ * LC / 4), dim3(256), 0, stream, S, Qmask, rowmax, rowsum);
    hipLaunchKernelGGL(k_colstats, dim3(LQ / 64, B_), dim3(256), 0, stream, S, Cmask, colmax, colsum);
    hipLaunchKernelGGL(k_V2, dim3((LQ / 64) * (D_ / 64), B_), dim3(256), 0, stream,
                       S, C, Cmask, colmax, colsum, V2t);
    hipLaunchKernelGGL(k_out, dim3((LC / 64) * 4, B_), dim3(256), 0, stream,
                       S, Q, V2t, C, Qmask, rowmax, rowsum, out);
    hipLaunchKernelGGL(k_copy, dim3(B_ * D_ * LC / 4 / 256), dim3(256), 0, stream, C, out);
}

// Round 3
// 567.372 us; speedup vs baseline: 2.6964x; 2.6964x over previous
//
#include <hip/hip_runtime.h>

#define B_ 32
#define D_ 128
#define LC 2048
#define LQ 512

#define NEGINF (-3.0e38f)

typedef __attribute__((ext_vector_type(8))) short bf16x8;
typedef __attribute__((ext_vector_type(4))) float f32x4;
typedef __attribute__((ext_vector_type(8))) unsigned short us8;
typedef __attribute__((ext_vector_type(8))) _Float16 f16x8;

__device__ __forceinline__ unsigned short bf16rne(float x) {
    unsigned int u = __float_as_uint(x);
    u = (u + 0x7FFFu + ((u >> 16) & 1u)) >> 16;
    return (unsigned short)u;
}

__device__ __forceinline__ void gll16(const void* g, void* l) {
    __builtin_amdgcn_global_load_lds((const __attribute__((address_space(1))) void*)g,
                                     (__attribute__((address_space(3))) void*)l, 16, 0, 0);
}

// ---------- K0: outv[b,x] = sum_d X[b,d,x] * w[d] ----------
__global__ void k_dotw(const float* __restrict__ X, const float* __restrict__ w,
                       float* __restrict__ outv, int L) {
    int idx = blockIdx.x * 256 + threadIdx.x;
    int b = idx / L, x = idx - b * L;
    const float* Xp = X + (size_t)b * D_ * L + x;
    float acc = 0.f;
#pragma unroll 8
    for (int dd = 0; dd < D_; ++dd) acc += Xp[(size_t)dd * L] * w[dd];
    outv[idx] = acc;
}

// ---------- prep C: Ctw[c][d] = bf16(C[d][c]*wmul[d]) (transposed), Cb16[d][c] = bf16(C[d][c]) ----------
__global__ void k_prep_C(const float* __restrict__ C, const float* __restrict__ wmul,
                         short* __restrict__ Ctw, short* __restrict__ Cb16) {
    int b = blockIdx.y, c0 = blockIdx.x * 64;
    __shared__ float Tf[128][65];
    __shared__ float wm[128];
    int t = threadIdx.x;
    if (t < 128) wm[t] = wmul[t];
    const float* Cb = C + (size_t)b * D_ * LC;
#pragma unroll
    for (int i = 0; i < 8; ++i) {
        int idx = t + i * 256;
        int d = idx >> 4, c4 = idx & 15;
        float4 v = *(const float4*)(Cb + (size_t)d * LC + c0 + c4 * 4);
        Tf[d][c4 * 4 + 0] = v.x; Tf[d][c4 * 4 + 1] = v.y;
        Tf[d][c4 * 4 + 2] = v.z; Tf[d][c4 * 4 + 3] = v.w;
        ushort4 cv;
        cv.x = bf16rne(v.x); cv.y = bf16rne(v.y); cv.z = bf16rne(v.z); cv.w = bf16rne(v.w);
        *(ushort4*)(Cb16 + ((size_t)b * D_ + d) * LC + c0 + c4 * 4) = cv;
    }
    __syncthreads();
    int c_l = t & 63, g = t >> 6;
    unsigned short u[32];
#pragma unroll
    for (int j = 0; j < 32; ++j) {
        int d = g * 32 + j;
        u[j] = bf16rne(Tf[d][c_l] * wm[d]);
    }
    short* dst = Ctw + ((size_t)b * LC + c0 + c_l) * D_ + g * 32;
#pragma unroll
    for (int k = 0; k < 4; ++k) *(us8*)(dst + k * 8) = *(const us8*)&u[k * 8];
}

// ---------- prep Q: Qt16[q][d] = bf16(Q[d][q]) (transposed), W[n=d][q] = bf16(Q[d][q]) ----------
__global__ void k_prep_Q(const float* __restrict__ Q, short* __restrict__ Qt16,
                         short* __restrict__ Wf) {
    int b = blockIdx.y, q0 = blockIdx.x * 64;
    __shared__ float Tf[128][65];
    int t = threadIdx.x;
    const float* Qb = Q + (size_t)b * D_ * LQ;
#pragma unroll
    for (int i = 0; i < 8; ++i) {
        int idx = t + i * 256;
        int d = idx >> 4, q4 = idx & 15;
        float4 v = *(const float4*)(Qb + (size_t)d * LQ + q0 + q4 * 4);
        Tf[d][q4 * 4 + 0] = v.x; Tf[d][q4 * 4 + 1] = v.y;
        Tf[d][q4 * 4 + 2] = v.z; Tf[d][q4 * 4 + 3] = v.w;
        ushort4 cv;
        cv.x = bf16rne(v.x); cv.y = bf16rne(v.y); cv.z = bf16rne(v.z); cv.w = bf16rne(v.w);
        *(ushort4*)(Wf + ((size_t)b * 256 + d) * LQ + q0 + q4 * 4) = cv;
    }
    __syncthreads();
    int q_l = t & 63, g = t >> 6;
    unsigned short u[32];
#pragma unroll
    for (int j = 0; j < 32; ++j) u[j] = bf16rne(Tf[g * 32 + j][q_l]);
    short* dst = Qt16 + ((size_t)b * LQ + q0 + q_l) * D_ + g * 32;
#pragma unroll
    for (int k = 0; k < 4; ++k) *(us8*)(dst + k * 8) = *(const us8*)&u[k * 8];
}

// ---------- K1: S[c][q] via MFMA, stored fp16 ----------
__global__ __launch_bounds__(256) void k_S_mfma(const short* __restrict__ Ctw,
                                                const short* __restrict__ Qt16,
                                                const float* __restrict__ s0,
                                                const float* __restrict__ s1,
                                                const float* __restrict__ bias,
                                                _Float16* __restrict__ S16) {
    int b = blockIdx.y;
    int cT = blockIdx.x >> 2, qT = blockIdx.x & 3;
    int c0 = cT * 128, q0 = qT * 128;
    int t = threadIdx.x, w = t >> 6, l = t & 63;
    int wm_ = w >> 1, wn = w & 1;
    __shared__ short As[128 * 64];
    __shared__ short Bs[128 * 64];
    f32x4 acc[4][4] = {};
    const short* Arow = Ctw + ((size_t)b * LC + c0) * D_;
    const short* Brow = Qt16 + ((size_t)b * LQ + q0) * D_;
    int lr = l >> 3, sl = l & 7;
    for (int kt = 0; kt < 2; ++kt) {
        __syncthreads();
#pragma unroll
        for (int i = 0; i < 4; ++i) {
            int r = w * 32 + i * 8 + lr;
            int g = sl ^ (r & 7);
            gll16(Arow + (size_t)r * D_ + kt * 64 + g * 8, &As[(w * 32 + i * 8) * 64]);
            gll16(Brow + (size_t)r * D_ + kt * 64 + g * 8, &Bs[(w * 32 + i * 8) * 64]);
        }
        __syncthreads();
#pragma unroll
        for (int ks = 0; ks < 2; ++ks) {
            int kg = ks * 4 + (l >> 4);
            bf16x8 af[4], bfr[4];
#pragma unroll
            for (int ms = 0; ms < 4; ++ms) {
                int m = wm_ * 64 + ms * 16 + (l & 15);
                af[ms] = *(const bf16x8*)&As[m * 64 + (kg ^ (m & 7)) * 8];
            }
#pragma unroll
            for (int ns = 0; ns < 4; ++ns) {
                int n = wn * 64 + ns * 16 + (l & 15);
                bfr[ns] = *(const bf16x8*)&Bs[n * 64 + (kg ^ (n & 7)) * 8];
            }
#pragma unroll
            for (int ms = 0; ms < 4; ++ms)
#pragma unroll
                for (int ns = 0; ns < 4; ++ns)
                    acc[ms][ns] = __builtin_amdgcn_mfma_f32_16x16x32_bf16(af[ms], bfr[ns], acc[ms][ns], 0, 0, 0);
        }
    }
    float bv = bias[0];
#pragma unroll
    for (int ms = 0; ms < 4; ++ms) {
        int cb = c0 + wm_ * 64 + ms * 16 + (l >> 4) * 4;
#pragma unroll
        for (int ns = 0; ns < 4; ++ns) {
            int q = q0 + wn * 64 + ns * 16 + (l & 15);
            float s1v = s1[b * LQ + q] + bv;
#pragma unroll
            for (int r = 0; r < 4; ++r) {
                int c = cb + r;
                S16[((size_t)b * LC + c) * LQ + q] = (_Float16)(acc[ms][ns][r] + s0[b * LC + c] + s1v);
            }
        }
    }
}

// ---------- K2: row stats (over q) ----------
__global__ void k_rowstats(const _Float16* __restrict__ S16, const int* __restrict__ Qmask,
                           float* __restrict__ rowmax, float* __restrict__ rowsum) {
    int row = blockIdx.x * 4 + (threadIdx.x >> 6);
    int lane = threadIdx.x & 63;
    int b = row / LC;
    f16x8 v = *(const f16x8*)(S16 + (size_t)row * LQ + lane * 8);
    const int* qm = Qmask + b * LQ + lane * 8;
    int4 m0 = *(const int4*)qm;
    int4 m1 = *(const int4*)(qm + 4);
    int mk[8] = {m0.x, m0.y, m0.z, m0.w, m1.x, m1.y, m1.z, m1.w};
    float vf[8];
#pragma unroll
    for (int k = 0; k < 8; ++k) vf[k] = (float)v[k];
    float mx = NEGINF;
#pragma unroll
    for (int k = 0; k < 8; ++k) if (mk[k]) mx = fmaxf(mx, vf[k]);
#pragma unroll
    for (int off = 32; off > 0; off >>= 1) mx = fmaxf(mx, __shfl_xor(mx, off, 64));
    float s = 0.f;
#pragma unroll
    for (int k = 0; k < 8; ++k) if (mk[k]) s += __expf(vf[k] - mx);
#pragma unroll
    for (int off = 32; off > 0; off >>= 1) s += __shfl_xor(s, off, 64);
    if (lane == 0) { rowmax[row] = mx; rowsum[row] = s; }
}

// ---------- K3: col stats (over c) ----------
__global__ void k_colstats(const _Float16* __restrict__ S16, const int* __restrict__ Cmask,
                           float* __restrict__ colmax, float* __restrict__ colsum) {
    int b = blockIdx.y;
    int q0 = blockIdx.x * 64;
    int tid = threadIdx.x;
    int ql = tid & 63, cg = tid >> 6;
    const _Float16* Sb = S16 + (size_t)b * LC * LQ + q0 + ql;
    const int* cm = Cmask + b * LC;
    float m = NEGINF, lsum = 0.f;
    for (int c = cg; c < LC; c += 4) {
        if (cm[c]) {
            float v = (float)Sb[(size_t)c * LQ];
            float mn = fmaxf(m, v);
            lsum = lsum * __expf(m - mn) + __expf(v - mn);
            m = mn;
        }
    }
    __shared__ float Ms[4][64], Ls[4][64];
    Ms[cg][ql] = m; Ls[cg][ql] = lsum;
    __syncthreads();
    if (tid < 64) {
        float mm = Ms[0][ql], ll = Ls[0][ql];
#pragma unroll
        for (int g = 1; g < 4; ++g) {
            float m2 = Ms[g][ql], l2 = Ls[g][ql];
            float mn = fmaxf(mm, m2);
            ll = ll * __expf(mm - mn) + l2 * __expf(m2 - mn);
            mm = mn;
        }
        colmax[b * LQ + q0 + ql] = mm;
        colsum[b * LQ + q0 + ql] = ll;
    }
}

// ---------- K5: Wf[128+dd][q] = bf16( (1/colsum[q]) * sum_c Cb16[dd][c]*cm[c]*exp(S[c][q]-colmax[q]) )
// A = Cb16[dd][c] (gll16, xor swizzle); B = E2t[q][c] transpose-staged on the fly from S16.
__global__ __launch_bounds__(256) void k_V2_mfma(const short* __restrict__ Cb16,
                                                 const _Float16* __restrict__ S16,
                                                 const int* __restrict__ Cmask,
                                                 const float* __restrict__ colmax,
                                                 const float* __restrict__ colsum,
                                                 short* __restrict__ Wf) {
    int b = blockIdx.y;
    int q0 = blockIdx.x * 64;
    int t = threadIdx.x, w = t >> 6, l = t & 63;
    __shared__ short As[128 * 64];    // [dd][c-chunk 64], xor swizzle
    __shared__ short Bs[64 * 72];     // [q][c-chunk 64], pad to 72
    f32x4 acc[2][4] = {};
    const short* Arow = Cb16 + (size_t)b * D_ * LC;
    int lr = l >> 3, sl = l & 7;
    // per-thread B-staging role: c = l within chunk, q = q0 + w*16 .. +15
    float cmx[16];
#pragma unroll
    for (int j2 = 0; j2 < 4; ++j2)
        *(float4*)&cmx[j2 * 4] = *(const float4*)(colmax + b * LQ + q0 + w * 16 + j2 * 4);
    const _Float16* Sq = S16 + (size_t)b * LC * LQ + q0 + w * 16;
    const int* cmb = Cmask + b * LC;

    for (int kt = 0; kt < 32; ++kt) {
        int ck = kt * 64;
        __syncthreads();
#pragma unroll
        for (int i = 0; i < 4; ++i) {
            int r = w * 32 + i * 8 + lr;
            int g = sl ^ (r & 7);
            gll16(Arow + (size_t)r * LC + ck + g * 8, &As[(w * 32 + i * 8) * 64]);
        }
        {   // transpose-stage B with exp
            float cmf = (float)cmb[ck + l];
            const _Float16* sp = Sq + (size_t)(ck + l) * LQ;
            f16x8 v0 = *(const f16x8*)sp;
            f16x8 v1 = *(const f16x8*)(sp + 8);
#pragma unroll
            for (int j = 0; j < 8; ++j)
                Bs[(w * 16 + j) * 72 + l] = (short)bf16rne(cmf * __expf((float)v0[j] - cmx[j]));
#pragma unroll
            for (int j = 0; j < 8; ++j)
                Bs[(w * 16 + 8 + j) * 72 + l] = (short)bf16rne(cmf * __expf((float)v1[j] - cmx[8 + j]));
        }
        __syncthreads();
#pragma unroll
        for (int ks = 0; ks < 2; ++ks) {
            int kg = ks * 4 + (l >> 4);
            bf16x8 af[2], bfr[4];
#pragma unroll
            for (int ms = 0; ms < 2; ++ms) {
                int m = w * 32 + ms * 16 + (l & 15);
                af[ms] = *(const bf16x8*)&As[m * 64 + (kg ^ (m & 7)) * 8];
            }
#pragma unroll
            for (int ns = 0; ns < 4; ++ns) {
                int n = ns * 16 + (l & 15);
                bfr[ns] = *(const bf16x8*)&Bs[n * 72 + kg * 8];
            }
#pragma unroll
            for (int ms = 0; ms < 2; ++ms)
#pragma unroll
                for (int ns = 0; ns < 4; ++ns)
                    acc[ms][ns] = __builtin_amdgcn_mfma_f32_16x16x32_bf16(af[ms], bfr[ns], acc[ms][ns], 0, 0, 0);
        }
    }
#pragma unroll
    for (int ms = 0; ms < 2; ++ms)
#pragma unroll
        for (int ns = 0; ns < 4; ++ns) {
            int q = q0 + ns * 16 + (l & 15);
            float csi = 1.0f / colsum[b * LQ + q];
#pragma unroll
            for (int r = 0; r < 4; ++r) {
                int dd = w * 32 + ms * 16 + (l >> 4) * 4 + r;
                Wf[((size_t)b * 256 + 128 + dd) * LQ + q] = (short)bf16rne(acc[ms][ns][r] * csi);
            }
        }
}

// ---------- K6: OUT^T GEMM: A=W[n][q] (gll16), B=E1 on-the-fly from fp16 S ----------
__global__ __launch_bounds__(256) void k_out_mfma(const _Float16* __restrict__ S16,
                                                  const short* __restrict__ Wf,
                                                  const float* __restrict__ C,
                                                  const int* __restrict__ Qmask,
                                                  const float* __restrict__ rowmax,
                                                  const float* __restrict__ rowsum,
                                                  float* __restrict__ out) {
    int b = blockIdx.y;
    int cT = blockIdx.x >> 1, nT = blockIdx.x & 1;
    int c0 = cT * 128;
    int t = threadIdx.x, w = t >> 6, l = t & 63;
    int wm_ = w >> 1, wc = w & 1;
    __shared__ short As[128 * 64];
    __shared__ short Bs[128 * 72];
    f32x4 acc[4][4] = {};
    int br = t >> 1, bh = t & 1;
    float rm = rowmax[b * LC + c0 + br];
    float ri = 1.0f / rowsum[b * LC + c0 + br];
    const _Float16* Srow = S16 + ((size_t)b * LC + c0 + br) * LQ;
    const int* qmb = Qmask + b * LQ;
    const short* Arow = Wf + ((size_t)b * 256 + nT * 128) * LQ;
    int lr = l >> 3, sl = l & 7;
    for (int kt = 0; kt < 8; ++kt) {
        int qk = kt * 64;
        __syncthreads();
#pragma unroll
        for (int i = 0; i < 4; ++i) {
            int r = w * 32 + i * 8 + lr;
            int g = sl ^ (r & 7);
            gll16(Arow + (size_t)r * LQ + qk + g * 8, &As[(w * 32 + i * 8) * 64]);
        }
#pragma unroll
        for (int j2 = 0; j2 < 4; ++j2) {
            int qo = qk + bh * 32 + j2 * 8;
            f16x8 v = *(const f16x8*)(Srow + qo);
            int4 qa = *(const int4*)(qmb + qo);
            int4 qb = *(const int4*)(qmb + qo + 4);
            unsigned short u[8];
            u[0] = qa.x ? bf16rne(__expf((float)v[0] - rm) * ri) : (unsigned short)0;
            u[1] = qa.y ? bf16rne(__expf((float)v[1] - rm) * ri) : (unsigned short)0;
            u[2] = qa.z ? bf16rne(__expf((float)v[2] - rm) * ri) : (unsigned short)0;
            u[3] = qa.w ? bf16rne(__expf((float)v[3] - rm) * ri) : (unsigned short)0;
            u[4] = qb.x ? bf16rne(__expf((float)v[4] - rm) * ri) : (unsigned short)0;
            u[5] = qb.y ? bf16rne(__expf((float)v[5] - rm) * ri) : (unsigned short)0;
            u[6] = qb.z ? bf16rne(__expf((float)v[6] - rm) * ri) : (unsigned short)0;
            u[7] = qb.w ? bf16rne(__expf((float)v[7] - rm) * ri) : (unsigned short)0;
            *(us8*)&Bs[br * 72 + bh * 32 + j2 * 8] = *(const us8*)&u[0];
        }
        __syncthreads();
#pragma unroll
        for (int ks = 0; ks < 2; ++ks) {
            int kg = ks * 4 + (l >> 4);
            bf16x8 af[4], bfr[4];
#pragma unroll
            for (int ms = 0; ms < 4; ++ms) {
                int m = wm_ * 64 + ms * 16 + (l & 15);
                af[ms] = *(const bf16x8*)&As[m * 64 + (kg ^ (m & 7)) * 8];
            }
#pragma unroll
            for (int ns = 0; ns < 4; ++ns) {
                int cc = wc * 64 + ns * 16 + (l & 15);
                bfr[ns] = *(const bf16x8*)&Bs[cc * 72 + kg * 8];
            }
#pragma unroll
            for (int ms = 0; ms < 4; ++ms)
#pragma unroll
                for (int ns = 0; ns < 4; ++ns)
                    acc[ms][ns] = __builtin_amdgcn_mfma_f32_16x16x32_bf16(af[ms], bfr[ns], acc[ms][ns], 0, 0, 0);
        }
    }
#pragma unroll
    for (int ms = 0; ms < 4; ++ms) {
        int nb = nT * 128 + wm_ * 64 + ms * 16 + (l >> 4) * 4;
#pragma unroll
        for (int ns = 0; ns < 4; ++ns) {
            int c = c0 + wc * 64 + ns * 16 + (l & 15);
#pragma unroll
            for (int r = 0; r < 4; ++r) {
                int n = nb + r;
                float a = acc[ms][ns][r];
                if (n < 128) {
                    float cv = C[((size_t)b * D_ + n) * LC + c];
                    out[((size_t)b * 512 + 128 + n) * LC + c] = a;
                    out[((size_t)b * 512 + 256 + n) * LC + c] = cv * a;
                } else {
                    int dd = n - 128;
                    float cv = C[((size_t)b * D_ + dd) * LC + c];
                    out[((size_t)b * 512 + 384 + dd) * LC + c] = cv * a;
                }
            }
        }
    }
}

// ---------- K7: out[b, 0:128, c] = C ----------
__global__ void k_copy(const float* __restrict__ C, float* __restrict__ out) {
    int idx = blockIdx.x * 256 + threadIdx.x;
    const int perB = D_ * LC / 4;
    int b = idx / perB, r = idx - b * perB;
    const float4* src = (const float4*)(C + (size_t)b * D_ * LC);
    float4* dst = (float4*)(out + (size_t)b * 4 * D_ * LC);
    dst[r] = src[r];
}

extern "C" void kernel_launch(void* const* d_in, const int* in_sizes, int n_in,
                              void* d_out, int out_size, void* d_ws, size_t ws_size,
                              hipStream_t stream) {
    const float* C     = (const float*)d_in[0];
    const float* Q     = (const float*)d_in[1];
    const int*   Cmask = (const int*)d_in[2];
    const int*   Qmask = (const int*)d_in[3];
    const float* w_c   = (const float*)d_in[4];
    const float* w_q   = (const float*)d_in[5];
    const float* w_mul = (const float*)d_in[6];
    const float* bias  = (const float*)d_in[7];
    float* out = (float*)d_out;

    // workspace layout: 114.2 MB total (< 143.6 MB proven safe in round 1)
    _Float16* S16 = (_Float16*)d_ws;                      // B*LC*LQ fp16  = 67.1 MB
    short* Cb16 = (short*)(S16 + (size_t)B_ * LC * LQ);   // B*D*LC bf16   = 16.8 MB
    short* Ctw  = Cb16 + (size_t)B_ * D_ * LC;            // B*LC*D bf16   = 16.8 MB
    short* Qt16 = Ctw + (size_t)B_ * LC * D_;             // B*LQ*D bf16   =  4.2 MB
    short* Wf   = Qt16 + (size_t)B_ * LQ * D_;            // B*256*LQ bf16 =  8.4 MB
    float* s0     = (float*)(Wf + (size_t)B_ * 256 * LQ); // B*LC
    float* s1     = s0 + B_ * LC;                         // B*LQ
    float* rowmax = s1 + B_ * LQ;                         // B*LC
    float* rowsum = rowmax + B_ * LC;                     // B*LC
    float* colmax = rowsum + B_ * LC;                     // B*LQ
    float* colsum = colmax + B_ * LQ;                     // B*LQ

    hipLaunchKernelGGL(k_dotw, dim3(B_ * LC / 256), dim3(256), 0, stream, C, w_c, s0, LC);
    hipLaunchKernelGGL(k_dotw, dim3(B_ * LQ / 256), dim3(256), 0, stream, Q, w_q, s1, LQ);
    hipLaunchKernelGGL(k_prep_C, dim3(LC / 64, B_), dim3(256), 0, stream, C, w_mul, Ctw, Cb16);
    hipLaunchKernelGGL(k_prep_Q, dim3(LQ / 64, B_), dim3(256), 0, stream, Q, Qt16, Wf);
    hipLaunchKernelGGL(k_S_mfma, dim3((LC / 128) * (LQ / 128), B_), dim3(256), 0, stream,
                       Ctw, Qt16, s0, s1, bias, S16);
    hipLaunchKernelGGL(k_rowstats, dim3(B_ * LC / 4), dim3(256), 0, stream, S16, Qmask, rowmax, rowsum);
    hipLaunchKernelGGL(k_colstats, dim3(LQ / 64, B_), dim3(256), 0, stream, S16, Cmask, colmax, colsum);
    hipLaunchKernelGGL(k_V2_mfma, dim3(LQ / 64, B_), dim3(256), 0, stream,
                       Cb16, S16, Cmask, colmax, colsum, Wf);
    hipLaunchKernelGGL(k_out_mfma, dim3((LC / 128) * 2, B_), dim3(256), 0, stream,
                       S16, Wf, C, Qmask, rowmax, rowsum, out);
    hipLaunchKernelGGL(k_copy, dim3(B_ * D_ * LC / 4 / 256), dim3(256), 0, stream, C, out);
}

// Round 4
// 426.275 us; speedup vs baseline: 3.5889x; 1.3310x over previous
//
#include <hip/hip_runtime.h>

#define B_ 32
#define D_ 128
#define LC 2048
#define LQ 512
#define CCH 16   // c-chunks for colstats partials

#define NEGINF (-3.0e38f)

typedef __attribute__((ext_vector_type(8))) short bf16x8;
typedef __attribute__((ext_vector_type(4))) float f32x4;
typedef __attribute__((ext_vector_type(8))) unsigned short us8;
typedef __attribute__((ext_vector_type(8))) _Float16 f16x8;

__device__ __forceinline__ unsigned short bf16rne(float x) {
    unsigned int u = __float_as_uint(x);
    u = (u + 0x7FFFu + ((u >> 16) & 1u)) >> 16;
    return (unsigned short)u;
}

__device__ __forceinline__ void gll16(const void* g, void* l) {
    __builtin_amdgcn_global_load_lds((const __attribute__((address_space(1))) void*)g,
                                     (__attribute__((address_space(3))) void*)l, 16, 0, 0);
}

// ---------- K0: outv[b,x] = sum_d X[b,d,x] * w[d] ----------
__global__ void k_dotw(const float* __restrict__ X, const float* __restrict__ w,
                       float* __restrict__ outv, int L) {
    int idx = blockIdx.x * 256 + threadIdx.x;
    int b = idx / L, x = idx - b * L;
    const float* Xp = X + (size_t)b * D_ * L + x;
    float acc = 0.f;
#pragma unroll 8
    for (int dd = 0; dd < D_; ++dd) acc += Xp[(size_t)dd * L] * w[dd];
    outv[idx] = acc;
}

// ---------- prep C: Ctw[c][d] = bf16(C[d][c]*wmul[d]) (transposed), Cb16[d][c] = bf16(C[d][c]) ----------
__global__ void k_prep_C(const float* __restrict__ C, const float* __restrict__ wmul,
                         short* __restrict__ Ctw, short* __restrict__ Cb16) {
    int b = blockIdx.y, c0 = blockIdx.x * 64;
    __shared__ float Tf[128][65];
    __shared__ float wm[128];
    int t = threadIdx.x;
    if (t < 128) wm[t] = wmul[t];
    const float* Cb = C + (size_t)b * D_ * LC;
#pragma unroll
    for (int i = 0; i < 8; ++i) {
        int idx = t + i * 256;
        int d = idx >> 4, c4 = idx & 15;
        float4 v = *(const float4*)(Cb + (size_t)d * LC + c0 + c4 * 4);
        Tf[d][c4 * 4 + 0] = v.x; Tf[d][c4 * 4 + 1] = v.y;
        Tf[d][c4 * 4 + 2] = v.z; Tf[d][c4 * 4 + 3] = v.w;
        ushort4 cv;
        cv.x = bf16rne(v.x); cv.y = bf16rne(v.y); cv.z = bf16rne(v.z); cv.w = bf16rne(v.w);
        *(ushort4*)(Cb16 + ((size_t)b * D_ + d) * LC + c0 + c4 * 4) = cv;
    }
    __syncthreads();
    int c_l = t & 63, g = t >> 6;
    unsigned short u[32];
#pragma unroll
    for (int j = 0; j < 32; ++j) {
        int d = g * 32 + j;
        u[j] = bf16rne(Tf[d][c_l] * wm[d]);
    }
    short* dst = Ctw + ((size_t)b * LC + c0 + c_l) * D_ + g * 32;
#pragma unroll
    for (int k = 0; k < 4; ++k) *(us8*)(dst + k * 8) = *(const us8*)&u[k * 8];
}

// ---------- prep Q: Qt16[q][d] = bf16(Q[d][q]) (transposed), W[n=d][q] = bf16(Q[d][q]) ----------
__global__ void k_prep_Q(const float* __restrict__ Q, short* __restrict__ Qt16,
                         short* __restrict__ Wf) {
    int b = blockIdx.y, q0 = blockIdx.x * 64;
    __shared__ float Tf[128][65];
    int t = threadIdx.x;
    const float* Qb = Q + (size_t)b * D_ * LQ;
#pragma unroll
    for (int i = 0; i < 8; ++i) {
        int idx = t + i * 256;
        int d = idx >> 4, q4 = idx & 15;
        float4 v = *(const float4*)(Qb + (size_t)d * LQ + q0 + q4 * 4);
        Tf[d][q4 * 4 + 0] = v.x; Tf[d][q4 * 4 + 1] = v.y;
        Tf[d][q4 * 4 + 2] = v.z; Tf[d][q4 * 4 + 3] = v.w;
        ushort4 cv;
        cv.x = bf16rne(v.x); cv.y = bf16rne(v.y); cv.z = bf16rne(v.z); cv.w = bf16rne(v.w);
        *(ushort4*)(Wf + ((size_t)b * 256 + d) * LQ + q0 + q4 * 4) = cv;
    }
    __syncthreads();
    int q_l = t & 63, g = t >> 6;
    unsigned short u[32];
#pragma unroll
    for (int j = 0; j < 32; ++j) u[j] = bf16rne(Tf[g * 32 + j][q_l]);
    short* dst = Qt16 + ((size_t)b * LQ + q0 + q_l) * D_ + g * 32;
#pragma unroll
    for (int k = 0; k < 4; ++k) *(us8*)(dst + k * 8) = *(const us8*)&u[k * 8];
}

// ---------- K1: S[c][q] via MFMA, stored fp16 ----------
__global__ __launch_bounds__(256) void k_S_mfma(const short* __restrict__ Ctw,
                                                const short* __restrict__ Qt16,
                                                const float* __restrict__ s0,
                                                const float* __restrict__ s1,
                                                const float* __restrict__ bias,
                                                _Float16* __restrict__ S16) {
    int b = blockIdx.y;
    int cT = blockIdx.x >> 2, qT = blockIdx.x & 3;
    int c0 = cT * 128, q0 = qT * 128;
    int t = threadIdx.x, w = t >> 6, l = t & 63;
    int wm_ = w >> 1, wn = w & 1;
    __shared__ short As[128 * 64];
    __shared__ short Bs[128 * 64];
    f32x4 acc[4][4] = {};
    const short* Arow = Ctw + ((size_t)b * LC + c0) * D_;
    const short* Brow = Qt16 + ((size_t)b * LQ + q0) * D_;
    int lr = l >> 3, sl = l & 7;
    for (int kt = 0; kt < 2; ++kt) {
        __syncthreads();
#pragma unroll
        for (int i = 0; i < 4; ++i) {
            int r = w * 32 + i * 8 + lr;
            int g = sl ^ (r & 7);
            gll16(Arow + (size_t)r * D_ + kt * 64 + g * 8, &As[(w * 32 + i * 8) * 64]);
            gll16(Brow + (size_t)r * D_ + kt * 64 + g * 8, &Bs[(w * 32 + i * 8) * 64]);
        }
        __syncthreads();
#pragma unroll
        for (int ks = 0; ks < 2; ++ks) {
            int kg = ks * 4 + (l >> 4);
            bf16x8 af[4], bfr[4];
#pragma unroll
            for (int ms = 0; ms < 4; ++ms) {
                int m = wm_ * 64 + ms * 16 + (l & 15);
                af[ms] = *(const bf16x8*)&As[m * 64 + (kg ^ (m & 7)) * 8];
            }
#pragma unroll
            for (int ns = 0; ns < 4; ++ns) {
                int n = wn * 64 + ns * 16 + (l & 15);
                bfr[ns] = *(const bf16x8*)&Bs[n * 64 + (kg ^ (n & 7)) * 8];
            }
#pragma unroll
            for (int ms = 0; ms < 4; ++ms)
#pragma unroll
                for (int ns = 0; ns < 4; ++ns)
                    acc[ms][ns] = __builtin_amdgcn_mfma_f32_16x16x32_bf16(af[ms], bfr[ns], acc[ms][ns], 0, 0, 0);
        }
    }
    float bv = bias[0];
#pragma unroll
    for (int ms = 0; ms < 4; ++ms) {
        int cb = c0 + wm_ * 64 + ms * 16 + (l >> 4) * 4;
#pragma unroll
        for (int ns = 0; ns < 4; ++ns) {
            int q = q0 + wn * 64 + ns * 16 + (l & 15);
            float s1v = s1[b * LQ + q] + bv;
#pragma unroll
            for (int r = 0; r < 4; ++r) {
                int c = cb + r;
                S16[((size_t)b * LC + c) * LQ + q] = (_Float16)(acc[ms][ns][r] + s0[b * LC + c] + s1v);
            }
        }
    }
}

// ---------- K2: row stats (over q) ----------
__global__ void k_rowstats(const _Float16* __restrict__ S16, const int* __restrict__ Qmask,
                           float* __restrict__ rowmax, float* __restrict__ rowsum) {
    int row = blockIdx.x * 4 + (threadIdx.x >> 6);
    int lane = threadIdx.x & 63;
    int b = row / LC;
    f16x8 v = *(const f16x8*)(S16 + (size_t)row * LQ + lane * 8);
    const int* qm = Qmask + b * LQ + lane * 8;
    int4 m0 = *(const int4*)qm;
    int4 m1 = *(const int4*)(qm + 4);
    int mk[8] = {m0.x, m0.y, m0.z, m0.w, m1.x, m1.y, m1.z, m1.w};
    float vf[8];
#pragma unroll
    for (int k = 0; k < 8; ++k) vf[k] = (float)v[k];
    float mx = NEGINF;
#pragma unroll
    for (int k = 0; k < 8; ++k) if (mk[k]) mx = fmaxf(mx, vf[k]);
#pragma unroll
    for (int off = 32; off > 0; off >>= 1) mx = fmaxf(mx, __shfl_xor(mx, off, 64));
    float s = 0.f;
#pragma unroll
    for (int k = 0; k < 8; ++k) if (mk[k]) s += __expf(vf[k] - mx);
#pragma unroll
    for (int off = 32; off > 0; off >>= 1) s += __shfl_xor(s, off, 64);
    if (lane == 0) { rowmax[row] = mx; rowsum[row] = s; }
}

// ---------- K3a: col stats partials. grid (LQ/64, B, CCH); thread: (ql, cg) handles 32 c's ----------
__global__ __launch_bounds__(256) void k_colstats_part(const _Float16* __restrict__ S16,
                                                       const int* __restrict__ Cmask,
                                                       float* __restrict__ pm,
                                                       float* __restrict__ pl) {
    int b = blockIdx.y;
    int q0 = blockIdx.x * 64;
    int ch = blockIdx.z;
    int t = threadIdx.x, ql = t & 63, cg = t >> 6;
    const int cbase = ch * (LC / CCH);              // 128 c per chunk
    const _Float16* Sb = S16 + (size_t)b * LC * LQ + (size_t)cbase * LQ + q0 + ql;
    const int* cm = Cmask + b * LC + cbase;
    // c = cbase + cg + 4*i, i in 0..31 — all loads independent, branch-free mask
    float v[32];
#pragma unroll
    for (int i = 0; i < 32; ++i) {
        int c = cg + 4 * i;
        float x = (float)Sb[(size_t)c * LQ];
        v[i] = cm[c] ? x : NEGINF;                  // cm wave-uniform -> s_load + cndmask
    }
    float m8[8];
#pragma unroll
    for (int j = 0; j < 8; ++j) m8[j] = v[j];
#pragma unroll
    for (int i = 8; i < 32; ++i) m8[i & 7] = fmaxf(m8[i & 7], v[i]);
    float m = fmaxf(fmaxf(fmaxf(m8[0], m8[1]), fmaxf(m8[2], m8[3])),
                    fmaxf(fmaxf(m8[4], m8[5]), fmaxf(m8[6], m8[7])));
    float s8[8];
#pragma unroll
    for (int j = 0; j < 8; ++j) s8[j] = 0.f;
#pragma unroll
    for (int i = 0; i < 32; ++i) s8[i & 7] += __expf(v[i] - m);
    float l = ((s8[0] + s8[1]) + (s8[2] + s8[3])) + ((s8[4] + s8[5]) + (s8[6] + s8[7]));
    if (m == NEGINF) l = 0.f;                       // all-masked chunk: exp(0)=1 garbage
    __shared__ float Ms[4][64], Ls[4][64];
    Ms[cg][ql] = m; Ls[cg][ql] = l;
    __syncthreads();
    if (t < 64) {
        float mm = Ms[0][ql], ll = Ls[0][ql];
#pragma unroll
        for (int g = 1; g < 4; ++g) {
            float m2 = Ms[g][ql], l2 = Ls[g][ql];
            float mn = fmaxf(mm, m2);
            ll = ll * __expf(mm - mn) + l2 * __expf(m2 - mn);
            mm = mn;
        }
        size_t o = ((size_t)ch * B_ + b) * LQ + q0 + ql;
        pm[o] = mm; pl[o] = ll;
    }
}

// ---------- K3b: combine CCH partials per column ----------
__global__ void k_colstats_comb(const float* __restrict__ pm, const float* __restrict__ pl,
                                float* __restrict__ colmax, float* __restrict__ colsum) {
    int idx = blockIdx.x * 256 + threadIdx.x;       // b*LQ + q
    float m = NEGINF, l = 0.f;
#pragma unroll
    for (int ch = 0; ch < CCH; ++ch) {
        float m2 = pm[(size_t)ch * B_ * LQ + idx];
        float l2 = pl[(size_t)ch * B_ * LQ + idx];
        float mn = fmaxf(m, m2);
        l = l * __expf(m - mn) + l2 * __expf(m2 - mn);
        m = mn;
    }
    colmax[idx] = m; colsum[idx] = l;
}

// ---------- K5: Wf[128+dd][q] = bf16( (1/colsum[q]) * sum_c Cb16[dd][c]*cm[c]*exp(S[c][q]-colmax[q]) ) ----------
__global__ __launch_bounds__(256) void k_V2_mfma(const short* __restrict__ Cb16,
                                                 const _Float16* __restrict__ S16,
                                                 const int* __restrict__ Cmask,
                                                 const float* __restrict__ colmax,
                                                 const float* __restrict__ colsum,
                                                 short* __restrict__ Wf) {
    int b = blockIdx.y;
    int q0 = blockIdx.x * 64;
    int t = threadIdx.x, w = t >> 6, l = t & 63;
    __shared__ short As[128 * 64];
    __shared__ short Bs[64 * 72];
    f32x4 acc[2][4] = {};
    const short* Arow = Cb16 + (size_t)b * D_ * LC;
    int lr = l >> 3, sl = l & 7;
    float cmx[16];
#pragma unroll
    for (int j2 = 0; j2 < 4; ++j2)
        *(float4*)&cmx[j2 * 4] = *(const float4*)(colmax + b * LQ + q0 + w * 16 + j2 * 4);
    const _Float16* Sq = S16 + (size_t)b * LC * LQ + q0 + w * 16;
    const int* cmb = Cmask + b * LC;

    for (int kt = 0; kt < 32; ++kt) {
        int ck = kt * 64;
        __syncthreads();
#pragma unroll
        for (int i = 0; i < 4; ++i) {
            int r = w * 32 + i * 8 + lr;
            int g = sl ^ (r & 7);
            gll16(Arow + (size_t)r * LC + ck + g * 8, &As[(w * 32 + i * 8) * 64]);
        }
        {
            float cmf = (float)cmb[ck + l];
            const _Float16* sp = Sq + (size_t)(ck + l) * LQ;
            f16x8 v0 = *(const f16x8*)sp;
            f16x8 v1 = *(const f16x8*)(sp + 8);
#pragma unroll
            for (int j = 0; j < 8; ++j)
                Bs[(w * 16 + j) * 72 + l] = (short)bf16rne(cmf * __expf((float)v0[j] - cmx[j]));
#pragma unroll
            for (int j = 0; j < 8; ++j)
                Bs[(w * 16 + 8 + j) * 72 + l] = (short)bf16rne(cmf * __expf((float)v1[j] - cmx[8 + j]));
        }
        __syncthreads();
#pragma unroll
        for (int ks = 0; ks < 2; ++ks) {
            int kg = ks * 4 + (l >> 4);
            bf16x8 af[2], bfr[4];
#pragma unroll
            for (int ms = 0; ms < 2; ++ms) {
                int m = w * 32 + ms * 16 + (l & 15);
                af[ms] = *(const bf16x8*)&As[m * 64 + (kg ^ (m & 7)) * 8];
            }
#pragma unroll
            for (int ns = 0; ns < 4; ++ns) {
                int n = ns * 16 + (l & 15);
                bfr[ns] = *(const bf16x8*)&Bs[n * 72 + kg * 8];
            }
#pragma unroll
            for (int ms = 0; ms < 2; ++ms)
#pragma unroll
                for (int ns = 0; ns < 4; ++ns)
                    acc[ms][ns] = __builtin_amdgcn_mfma_f32_16x16x32_bf16(af[ms], bfr[ns], acc[ms][ns], 0, 0, 0);
        }
    }
#pragma unroll
    for (int ms = 0; ms < 2; ++ms)
#pragma unroll
        for (int ns = 0; ns < 4; ++ns) {
            int q = q0 + ns * 16 + (l & 15);
            float csi = 1.0f / colsum[b * LQ + q];
#pragma unroll
            for (int r = 0; r < 4; ++r) {
                int dd = w * 32 + ms * 16 + (l >> 4) * 4 + r;
                Wf[((size_t)b * 256 + 128 + dd) * LQ + q] = (short)bf16rne(acc[ms][ns][r] * csi);
            }
        }
}

// ---------- K6: OUT^T GEMM ----------
__global__ __launch_bounds__(256) void k_out_mfma(const _Float16* __restrict__ S16,
                                                  const short* __restrict__ Wf,
                                                  const float* __restrict__ C,
                                                  const int* __restrict__ Qmask,
                                                  const float* __restrict__ rowmax,
                                                  const float* __restrict__ rowsum,
                                                  float* __restrict__ out) {
    int b = blockIdx.y;
    int cT = blockIdx.x >> 1, nT = blockIdx.x & 1;
    int c0 = cT * 128;
    int t = threadIdx.x, w = t >> 6, l = t & 63;
    int wm_ = w >> 1, wc = w & 1;
    __shared__ short As[128 * 64];
    __shared__ short Bs[128 * 72];
    f32x4 acc[4][4] = {};
    int br = t >> 1, bh = t & 1;
    float rm = rowmax[b * LC + c0 + br];
    float ri = 1.0f / rowsum[b * LC + c0 + br];
    const _Float16* Srow = S16 + ((size_t)b * LC + c0 + br) * LQ;
    const int* qmb = Qmask + b * LQ;
    const short* Arow = Wf + ((size_t)b * 256 + nT * 128) * LQ;
    int lr = l >> 3, sl = l & 7;
    for (int kt = 0; kt < 8; ++kt) {
        int qk = kt * 64;
        __syncthreads();
#pragma unroll
        for (int i = 0; i < 4; ++i) {
            int r = w * 32 + i * 8 + lr;
            int g = sl ^ (r & 7);
            gll16(Arow + (size_t)r * LQ + qk + g * 8, &As[(w * 32 + i * 8) * 64]);
        }
#pragma unroll
        for (int j2 = 0; j2 < 4; ++j2) {
            int qo = qk + bh * 32 + j2 * 8;
            f16x8 v = *(const f16x8*)(Srow + qo);
            int4 qa = *(const int4*)(qmb + qo);
            int4 qb = *(const int4*)(qmb + qo + 4);
            unsigned short u[8];
            u[0] = qa.x ? bf16rne(__expf((float)v[0] - rm) * ri) : (unsigned short)0;
            u[1] = qa.y ? bf16rne(__expf((float)v[1] - rm) * ri) : (unsigned short)0;
            u[2] = qa.z ? bf16rne(__expf((float)v[2] - rm) * ri) : (unsigned short)0;
            u[3] = qa.w ? bf16rne(__expf((float)v[3] - rm) * ri) : (unsigned short)0;
            u[4] = qb.x ? bf16rne(__expf((float)v[4] - rm) * ri) : (unsigned short)0;
            u[5] = qb.y ? bf16rne(__expf((float)v[5] - rm) * ri) : (unsigned short)0;
            u[6] = qb.z ? bf16rne(__expf((float)v[6] - rm) * ri) : (unsigned short)0;
            u[7] = qb.w ? bf16rne(__expf((float)v[7] - rm) * ri) : (unsigned short)0;
            *(us8*)&Bs[br * 72 + bh * 32 + j2 * 8] = *(const us8*)&u[0];
        }
        __syncthreads();
#pragma unroll
        for (int ks = 0; ks < 2; ++ks) {
            int kg = ks * 4 + (l >> 4);
            bf16x8 af[4], bfr[4];
#pragma unroll
            for (int ms = 0; ms < 4; ++ms) {
                int m = wm_ * 64 + ms * 16 + (l & 15);
                af[ms] = *(const bf16x8*)&As[m * 64 + (kg ^ (m & 7)) * 8];
            }
#pragma unroll
            for (int ns = 0; ns < 4; ++ns) {
                int cc = wc * 64 + ns * 16 + (l & 15);
                bfr[ns] = *(const bf16x8*)&Bs[cc * 72 + kg * 8];
            }
#pragma unroll
            for (int ms = 0; ms < 4; ++ms)
#pragma unroll
                for (int ns = 0; ns < 4; ++ns)
                    acc[ms][ns] = __builtin_amdgcn_mfma_f32_16x16x32_bf16(af[ms], bfr[ns], acc[ms][ns], 0, 0, 0);
        }
    }
#pragma unroll
    for (int ms = 0; ms < 4; ++ms) {
        int nb = nT * 128 + wm_ * 64 + ms * 16 + (l >> 4) * 4;
#pragma unroll
        for (int ns = 0; ns < 4; ++ns) {
            int c = c0 + wc * 64 + ns * 16 + (l & 15);
#pragma unroll
            for (int r = 0; r < 4; ++r) {
                int n = nb + r;
                float a = acc[ms][ns][r];
                if (n < 128) {
                    float cv = C[((size_t)b * D_ + n) * LC + c];
                    out[((size_t)b * 512 + 128 + n) * LC + c] = a;
                    out[((size_t)b * 512 + 256 + n) * LC + c] = cv * a;
                } else {
                    int dd = n - 128;
                    float cv = C[((size_t)b * D_ + dd) * LC + c];
                    out[((size_t)b * 512 + 384 + dd) * LC + c] = cv * a;
                }
            }
        }
    }
}

// ---------- K7: out[b, 0:128, c] = C ----------
__global__ void k_copy(const float* __restrict__ C, float* __restrict__ out) {
    int idx = blockIdx.x * 256 + threadIdx.x;
    const int perB = D_ * LC / 4;
    int b = idx / perB, r = idx - b * perB;
    const float4* src = (const float4*)(C + (size_t)b * D_ * LC);
    float4* dst = (float4*)(out + (size_t)b * 4 * D_ * LC);
    dst[r] = src[r];
}

extern "C" void kernel_launch(void* const* d_in, const int* in_sizes, int n_in,
                              void* d_out, int out_size, void* d_ws, size_t ws_size,
                              hipStream_t stream) {
    const float* C     = (const float*)d_in[0];
    const float* Q     = (const float*)d_in[1];
    const int*   Cmask = (const int*)d_in[2];
    const int*   Qmask = (const int*)d_in[3];
    const float* w_c   = (const float*)d_in[4];
    const float* w_q   = (const float*)d_in[5];
    const float* w_mul = (const float*)d_in[6];
    const float* bias  = (const float*)d_in[7];
    float* out = (float*)d_out;

    // workspace layout: ~116.3 MB total (< 143.6 MB proven safe in round 1)
    _Float16* S16 = (_Float16*)d_ws;                      // B*LC*LQ fp16  = 67.1 MB
    short* Cb16 = (short*)(S16 + (size_t)B_ * LC * LQ);   // B*D*LC bf16   = 16.8 MB
    short* Ctw  = Cb16 + (size_t)B_ * D_ * LC;            // B*LC*D bf16   = 16.8 MB
    short* Qt16 = Ctw + (size_t)B_ * LC * D_;             // B*LQ*D bf16   =  4.2 MB
    short* Wf   = Qt16 + (size_t)B_ * LQ * D_;            // B*256*LQ bf16 =  8.4 MB
    float* s0     = (float*)(Wf + (size_t)B_ * 256 * LQ); // B*LC
    float* s1     = s0 + B_ * LC;                         // B*LQ
    float* rowmax = s1 + B_ * LQ;                         // B*LC
    float* rowsum = rowmax + B_ * LC;                     // B*LC
    float* colmax = rowsum + B_ * LC;                     // B*LQ
    float* colsum = colmax + B_ * LQ;                     // B*LQ
    float* pm     = colsum + B_ * LQ;                     // CCH*B*LQ = 1 MB
    float* pl     = pm + (size_t)CCH * B_ * LQ;           // CCH*B*LQ = 1 MB

    hipLaunchKernelGGL(k_dotw, dim3(B_ * LC / 256), dim3(256), 0, stream, C, w_c, s0, LC);
    hipLaunchKernelGGL(k_dotw, dim3(B_ * LQ / 256), dim3(256), 0, stream, Q, w_q, s1, LQ);
    hipLaunchKernelGGL(k_prep_C, dim3(LC / 64, B_), dim3(256), 0, stream, C, w_mul, Ctw, Cb16);
    hipLaunchKernelGGL(k_prep_Q, dim3(LQ / 64, B_), dim3(256), 0, stream, Q, Qt16, Wf);
    hipLaunchKernelGGL(k_S_mfma, dim3((LC / 128) * (LQ / 128), B_), dim3(256), 0, stream,
                       Ctw, Qt16, s0, s1, bias, S16);
    hipLaunchKernelGGL(k_rowstats, dim3(B_ * LC / 4), dim3(256), 0, stream, S16, Qmask, rowmax, rowsum);
    hipLaunchKernelGGL(k_colstats_part, dim3(LQ / 64, B_, CCH), dim3(256), 0, stream,
                       S16, Cmask, pm, pl);
    hipLaunchKernelGGL(k_colstats_comb, dim3(B_ * LQ / 256), dim3(256), 0, stream,
                       pm, pl, colmax, colsum);
    hipLaunchKernelGGL(k_V2_mfma, dim3(LQ / 64, B_), dim3(256), 0, stream,
                       Cb16, S16, Cmask, colmax, colsum, Wf);
    hipLaunchKernelGGL(k_out_mfma, dim3((LC / 128) * 2, B_), dim3(256), 0, stream,
                       S16, Wf, C, Qmask, rowmax, rowsum, out);
    hipLaunchKernelGGL(k_copy, dim3(B_ * D_ * LC / 4 / 256), dim3(256), 0, stream, C, out);
}